// Round 10
// baseline (4620.311 us; speedup 1.0000x reference)
//
#include <hip/hip_runtime.h>

#define WAVE 64
#define BM 64
#define BN 64
#define BK 16
#define NBLK 256

// ---------------------------------------------------------------------------
// split pointcloud (B,N,6) -> xyz (B,N,3) + feats (B,N,3); zeros stats +
// barrier counters (ws re-poisoned 0xAA before every timed launch).
__global__ __launch_bounds__(256) void split_zero_kernel(const float* __restrict__ pc,
    float* __restrict__ xyz, float* __restrict__ feats, int total,
    float* __restrict__ stats, int n_stats) {
  int t = blockIdx.x * blockDim.x + threadIdx.x;
  if (t < n_stats) stats[t] = 0.f;
  if (t >= total) return;
  const float* p = pc + (size_t)t * 6;
  xyz[t * 3 + 0] = p[0]; xyz[t * 3 + 1] = p[1]; xyz[t * 3 + 2] = p[2];
  feats[t * 3 + 0] = p[3]; feats[t * 3 + 1] = p[4]; feats[t * 3 + 2] = p[5];
}

// ---------------------------------------------------------------------------
// Wave-wide reductions via DPP (VALU pipe only). rocPRIM pattern:
// row_shr 1/2/4/8 + row_bcast15/31; full max lands in lane 63.
__device__ __forceinline__ float dpp_max_f32(float v) {
#define DPP_STEP_F(ctrl) { int t_ = __builtin_amdgcn_update_dpp( \
      __float_as_int(v), __float_as_int(v), ctrl, 0xf, 0xf, false); \
    v = fmaxf(v, __int_as_float(t_)); }
  DPP_STEP_F(0x111) DPP_STEP_F(0x112) DPP_STEP_F(0x114)
  DPP_STEP_F(0x118) DPP_STEP_F(0x142) DPP_STEP_F(0x143)
#undef DPP_STEP_F
  return v;
}
__device__ __forceinline__ unsigned dpp_max_u32(unsigned v) {
#define DPP_STEP_U(ctrl) { unsigned t_ = (unsigned)__builtin_amdgcn_update_dpp( \
      (int)v, (int)v, ctrl, 0xf, 0xf, false); \
    v = (t_ > v) ? t_ : v; }
  DPP_STEP_U(0x111) DPP_STEP_U(0x112) DPP_STEP_U(0x114)
  DPP_STEP_U(0x118) DPP_STEP_U(0x142) DPP_STEP_U(0x143)
#undef DPP_STEP_U
  return v;
}
__device__ __forceinline__ unsigned bcast63(unsigned v) {
  return (unsigned)__builtin_amdgcn_readlane((int)v, 63);
}

// ---------------------------------------------------------------------------
// Generic small FPS level: NPTS points live in LDS arrays (sx/sy/sz), S picks.
// Writes winners to outp (global) and optionally mirrors into mx/my/mz (the
// next level's point set). Threads >= NPTS run the full machinery with
// mind = 0.0f (bit-pattern 0 => loses to any real key; on all-zero ties the
// inverted-index max still picks the smallest (active) index).
// Exact math: ((dx*dx+dy*dy)+dz*dz), explicit _rn, no FMA.
template<int NPTS>
__device__ void fps_level(const float* sx, const float* sy, const float* sz,
    int S, float* outp, float* mx, float* my, float* mz,
    unsigned long long* s_key) {
  const int tid = threadIdx.x;
  const int lane = tid & 63;
  float x = sx[tid & (NPTS - 1)], y = sy[tid & (NPTS - 1)], z = sz[tid & (NPTS - 1)];
  float mind = (tid < NPTS) ? 1e10f : 0.0f;
  if (tid < 3) s_key[tid] = 0ull;
  float qx = sx[0], qy = sy[0], qz = sz[0];
  if (tid == 0) {
    outp[0] = qx; outp[1] = qy; outp[2] = qz;
    if (mx) { mx[0] = qx; my[0] = qy; mz[0] = qz; }
  }
  __syncthreads();
  for (unsigned it = 1; it < (unsigned)S; ++it) {
    float dx = __fsub_rn(x, qx);
    float dy = __fsub_rn(y, qy);
    float dz = __fsub_rn(z, qz);
    float d = __fadd_rn(__fadd_rn(__fmul_rn(dx, dx), __fmul_rn(dy, dy)), __fmul_rn(dz, dz));
    mind = fminf(mind, d);
    float wm = dpp_max_f32(mind);
    unsigned wmb = bcast63(__float_as_uint(wm));
    unsigned cand = (__float_as_uint(mind) == wmb) ? (0xFFFFFFFFu - (unsigned)tid) : 0u;
    unsigned winv = bcast63(dpp_max_u32(cand));
    if (lane == 0) atomicMax(&s_key[it % 3u], ((unsigned long long)wmb << 32) | winv);
    if (tid == 0) s_key[(it + 1) % 3u] = 0ull;
    __syncthreads();
    unsigned long long k = s_key[it % 3u];
    int last = (int)(0xFFFFFFFFu - (unsigned)k);
    qx = sx[last]; qy = sy[last]; qz = sz[last];
    if (tid == 0) {
      float* o = outp + (size_t)it * 3;
      o[0] = qx; o[1] = qy; o[2] = qz;
      if (mx) { mx[it] = qx; my[it] = qy; mz[it] = qz; }
    }
  }
  __syncthreads();   // mirror writes complete before next level reads
}

// ---------------------------------------------------------------------------
// FPS mega-kernel: the whole 4-level FPS chain, one block per batch. The xyz
// chain depends only on xyz (never on the MLPs), and level l+1's points are
// exactly level l's winners — tid0 mirrors each winner into LDS for free.
// Level 0 is the proven round-4 structure (1691us, VALU-issue-bound).
__global__ __launch_bounds__(1024, 4) void fps_mega_kernel(const float* __restrict__ xyz,
    float* __restrict__ nx1, float* __restrict__ nx2, float* __restrict__ nx3,
    float* __restrict__ nx4) {
  const int b = blockIdx.x;
  const int tid = threadIdx.x;
  const int lane = tid & 63;
  __shared__ float s_ax[1024], s_ay[1024], s_az[1024];  // lvl1 pts; reused lvl3 pts
  __shared__ float s_bx[256], s_by[256], s_bz[256];     // lvl2 pts
  __shared__ unsigned long long s_key[3];
  const float* px = xyz + (size_t)b * 16384 * 3;
  {
    float rx[16], ry[16], rz[16], mind[16];
#pragma unroll
    for (int p = 0; p < 16; ++p) {
      int i = tid + p * 1024;
      rx[p] = px[i * 3 + 0]; ry[p] = px[i * 3 + 1]; rz[p] = px[i * 3 + 2];
      asm volatile("" : "+v"(rx[p]), "+v"(ry[p]), "+v"(rz[p]));
      mind[p] = 1e10f;
    }
    if (tid < 3) s_key[tid] = 0ull;
    float qx = px[0], qy = px[1], qz = px[2];   // pick 0 is always index 0
    if (tid == 0) {
      float* o = nx1 + (size_t)b * 1024 * 3;
      o[0] = qx; o[1] = qy; o[2] = qz;
      s_ax[0] = qx; s_ay[0] = qy; s_az[0] = qz;
    }
    __syncthreads();
    for (unsigned it = 1; it < 1024u; ++it) {
      float bestv = -1.f; unsigned besti = 0;
#pragma unroll
      for (int p = 0; p < 16; ++p) {
        float dx = __fsub_rn(rx[p], qx);
        float dy = __fsub_rn(ry[p], qy);
        float dz = __fsub_rn(rz[p], qz);
        float d = __fadd_rn(__fadd_rn(__fmul_rn(dx, dx), __fmul_rn(dy, dy)), __fmul_rn(dz, dz));
        float mo = fminf(mind[p], d);
        mind[p] = mo;
        if (mo > bestv) { bestv = mo; besti = (unsigned)(tid + p * 1024); }
      }
      float wm = dpp_max_f32(bestv);
      unsigned wmb = bcast63(__float_as_uint(wm));
      unsigned cand = (__float_as_uint(bestv) == wmb) ? (0xFFFFFFFFu - besti) : 0u;
      unsigned winv = bcast63(dpp_max_u32(cand));
      if (lane == 0) atomicMax(&s_key[it % 3u], ((unsigned long long)wmb << 32) | winv);
      if (tid == 0) s_key[(it + 1) % 3u] = 0ull;
      __syncthreads();
      unsigned long long k = s_key[it % 3u];
      int last = (int)(0xFFFFFFFFu - (unsigned)k);
      const float* q = px + (size_t)last * 3;   // broadcast L2 load
      qx = q[0]; qy = q[1]; qz = q[2];
      if (tid == 0) {
        float* o = nx1 + ((size_t)b * 1024 + it) * 3;
        o[0] = qx; o[1] = qy; o[2] = qz;
        s_ax[it] = qx; s_ay[it] = qy; s_az[it] = qz;
      }
    }
    __syncthreads();
  }
  fps_level<1024>(s_ax, s_ay, s_az, 256, nx2 + (size_t)b * 256 * 3,
                  s_bx, s_by, s_bz, s_key);
  fps_level<256>(s_bx, s_by, s_bz, 64, nx3 + (size_t)b * 64 * 3,
                 s_ax, s_ay, s_az, s_key);
  fps_level<64>(s_ax, s_ay, s_az, 16, nx4 + (size_t)b * 16 * 3,
                nullptr, nullptr, nullptr, s_key);
}

// ---------------------------------------------------------------------------
// Grid-wide barrier for the persistent chain kernel. Monotonic counter (no
// reset, no ABA); release-add + acquire-spin; __threadfence after the spin
// invalidates this CU's L1 (buffers are rewritten between stages).
__device__ __forceinline__ void grid_barrier(unsigned long long* cnt, unsigned stage) {
  __syncthreads();
  if (threadIdx.x == 0) {
    __threadfence();
    __hip_atomic_fetch_add(cnt, 1ull, __ATOMIC_RELEASE, __HIP_MEMORY_SCOPE_AGENT);
    unsigned long long tgt = (unsigned long long)gridDim.x * stage;
    while (__hip_atomic_load(cnt, __ATOMIC_ACQUIRE, __HIP_MEMORY_SCOPE_AGENT) < tgt)
      __builtin_amdgcn_s_sleep(2);
    __threadfence();
  }
  __syncthreads();
}

// ---------------------------------------------------------------------------
// One GEMM+stats stage of the persistent chain (grid-strided over tiles).
// Y(RxCo) = normReLU(A)(RxC) @ W(CxCo); per-channel sum/sumsq -> st_out.
__device__ void gemm_stage(const float* A, const float* W, float* Y,
    float* st_out, const float* st_in, const float* g_in, const float* b_in,
    int R, int C, int Co, float inv_n,
    float (*As)[BM + 4], float (*Bs)[BN + 4],
    float* s_mu, float* s_rs, float* s_g, float* s_b,
    float* s_sum, float* s_sq) {
  const int tid = threadIdx.x;
  if (st_in) {
    for (int c = tid; c < C; c += 256) {
      float mu = st_in[c] * inv_n;
      float var = st_in[512 + c] * inv_n - mu * mu;
      s_mu[c] = mu; s_rs[c] = rsqrtf(var + 1e-5f);
      s_g[c] = g_in[c]; s_b[c] = b_in[c];
    }
  }
  const int nrt = R >> 6;
  const int nct = (Co + 63) >> 6;
  const int ntiles = nrt * nct;
  const int tx = tid & 15, ty = tid >> 4;
  for (int tile = blockIdx.x; tile < ntiles; tile += gridDim.x) {
    int r0 = (tile % nrt) * BM;
    int n0 = (tile / nrt) * BN;
    __syncthreads();                 // guards s_sum/As reuse from previous tile
    if (tid < BN) { s_sum[tid] = 0.f; s_sq[tid] = 0.f; }
    __syncthreads();
    float acc[4][4] = {};
    for (int k0 = 0; k0 < C; k0 += BK) {
#pragma unroll
      for (int u = 0; u < 4; ++u) {
        int lin = tid + u * 256;
        int row = lin >> 4;
        int cc = lin & 15;
        int c = k0 + cc;
        float v = 0.f;
        if (c < C) {
          v = A[(size_t)(r0 + row) * C + c];
          if (st_in) {
            v = s_g[c] * ((v - s_mu[c]) * s_rs[c]) + s_b[c];
            v = v > 0.f ? v : 0.f;
          }
        }
        As[cc][row] = v;
      }
#pragma unroll
      for (int u = 0; u < 4; ++u) {
        int lin = tid + u * 256;
        int kk = lin >> 6;
        int n = lin & 63;
        int c = k0 + kk;
        Bs[kk][n] = (c < C && (n0 + n) < Co) ? W[(size_t)c * Co + n0 + n] : 0.f;
      }
      __syncthreads();
#pragma unroll
      for (int kk = 0; kk < BK; ++kk) {
        float a0[4], b0[4];
#pragma unroll
        for (int i = 0; i < 4; ++i) a0[i] = As[kk][ty * 4 + i];
#pragma unroll
        for (int jj = 0; jj < 4; ++jj) b0[jj] = Bs[kk][tx * 4 + jj];
#pragma unroll
        for (int i = 0; i < 4; ++i)
#pragma unroll
          for (int jj = 0; jj < 4; ++jj)
            acc[i][jj] = fmaf(a0[i], b0[jj], acc[i][jj]);
      }
      __syncthreads();
    }
#pragma unroll
    for (int i = 0; i < 4; ++i) {
      int r = r0 + ty * 4 + i;
#pragma unroll
      for (int jj = 0; jj < 4; ++jj) {
        int n = n0 + tx * 4 + jj;
        if (n < Co) Y[(size_t)r * Co + n] = acc[i][jj];
      }
    }
#pragma unroll
    for (int jj = 0; jj < 4; ++jj) {
      float cs = 0.f, cq = 0.f;
#pragma unroll
      for (int i = 0; i < 4; ++i) { float v = acc[i][jj]; cs += v; cq += v * v; }
      atomicAdd(&s_sum[tx * 4 + jj], cs);
      atomicAdd(&s_sq[tx * 4 + jj], cq);
    }
    __syncthreads();
    if (tid < BN) {
      int n = n0 + tid;
      if (n < Co) {
        atomicAdd(&st_out[n], s_sum[tid]);
        atomicAdd(&st_out[512 + n], s_sq[tid]);
      }
    }
  }
}

// ---------------------------------------------------------------------------
// Persistent per-layer chain: ballquery -> group -> 3x(GEMM+stats) -> norm-max,
// separated by grid barriers. grid = 256 blocks x 256 threads: worst-case
// packing (8 blocks/CU = 32 waves, 13.6KB LDS each) still co-resident, so the
// barrier cannot deadlock. Buffer ping-pong: X=bufA, Y1=bufB, Y2=bufA, Y3=bufB.
__global__ __launch_bounds__(256, 4) void layer_chain_kernel(
    const float* __restrict__ xyz, const float* __restrict__ feats,
    const float* __restrict__ centers, int* __restrict__ ballidx,
    float* __restrict__ bufA, float* __restrict__ bufB, float* __restrict__ outF,
    const float* __restrict__ W0, const float* __restrict__ g0, const float* __restrict__ b0,
    const float* __restrict__ W1, const float* __restrict__ g1, const float* __restrict__ b1,
    const float* __restrict__ W2, const float* __restrict__ g2, const float* __restrict__ b2,
    float* __restrict__ stats, unsigned long long* __restrict__ bar,
    int N, int S, int K, int ci, int c1, int c2, int c3, float r2, float inv_n) {
  __shared__ float As[BK][BM + 4];
  __shared__ float Bs[BK][BN + 4];
  __shared__ float s_mu[260], s_rs[260], s_g[260], s_b[260];
  __shared__ float s_sum[BN], s_sq[BN];
  const int tid = threadIdx.x;
  const int C0 = ci + 3;
  const int R = 8 * S * K;
  float* st0 = stats;
  float* st1 = stats + 1024;
  float* st2 = stats + 2048;

  // ---- stage 1: ball query (one wave per center, grid-strided) ----
  {
    const int gwave = (blockIdx.x * 256 + tid) >> 6;
    const int lane = tid & 63;
    const int nw = gridDim.x * 4;
    const int SG = 8 * S;
    for (int g = gwave; g < SG; g += nw) {
      int b = g / S;
      const float* px = xyz + (size_t)b * N * 3;
      const float* cp = centers + (size_t)g * 3;
      float cx = cp[0], cy = cp[1], cz = cp[2];
      int* outi = ballidx + (size_t)g * K;
      int cnt = 0, firsti = 0;
      for (int base = 0; base < N; base += WAVE) {
        int i = base + lane;
        float dx = __fsub_rn(cx, px[i * 3 + 0]);
        float dy = __fsub_rn(cy, px[i * 3 + 1]);
        float dz = __fsub_rn(cz, px[i * 3 + 2]);
        float d = __fadd_rn(__fadd_rn(__fmul_rn(dx, dx), __fmul_rn(dy, dy)), __fmul_rn(dz, dz));
        bool hit = d < r2;
        unsigned long long m = __ballot(hit);
        if (hit) {
          int slot = cnt + __popcll(m & ((1ull << lane) - 1ull));
          if (slot < K) outi[slot] = i;
        }
        if (cnt == 0 && m) firsti = base + __ffsll((unsigned long long)m) - 1;
        cnt += __popcll(m);
        if (cnt >= K) break;
      }
      for (int q = cnt + lane; q < K; q += WAVE) outi[q] = firsti;
    }
  }
  grid_barrier(bar, 1);

  // ---- stage 2: group X rows [xyz[j]-center (3), feats[j] (ci)] ----
  {
    long long total = (long long)R * C0;
    for (long long t = (long long)blockIdx.x * 256 + tid; t < total;
         t += (long long)gridDim.x * 256) {
      int r = (int)(t / C0);
      int c = (int)(t - (long long)r * C0);
      int g = r / K;
      int b = g / S;
      int j = ballidx[r];
      float v;
      if (c < 3) v = __fsub_rn(xyz[((size_t)b * N + j) * 3 + c], centers[(size_t)g * 3 + c]);
      else       v = feats[((size_t)b * N + j) * ci + (c - 3)];
      bufA[(size_t)r * C0 + c] = v;
    }
  }
  grid_barrier(bar, 2);

  // ---- stages 3-5: GEMM chain ----
  gemm_stage(bufA, W0, bufB, st0, nullptr, nullptr, nullptr, R, C0, c1, inv_n,
             As, Bs, s_mu, s_rs, s_g, s_b, s_sum, s_sq);
  grid_barrier(bar, 3);
  gemm_stage(bufB, W1, bufA, st1, st0, g0, b0, R, c1, c2, inv_n,
             As, Bs, s_mu, s_rs, s_g, s_b, s_sum, s_sq);
  grid_barrier(bar, 4);
  gemm_stage(bufA, W2, bufB, st2, st1, g1, b1, R, c2, c3, inv_n,
             As, Bs, s_mu, s_rs, s_g, s_b, s_sum, s_sq);
  grid_barrier(bar, 5);

  // ---- stage 6: normalize+relu+max over K ----
  {
    const int Gc = 8 * S;
    const int lc3 = 31 - __clz(c3);     // c3 is a power of two
    long long tot = (long long)Gc << lc3;
    for (long long t = (long long)blockIdx.x * 256 + tid; t < tot;
         t += (long long)gridDim.x * 256) {
      int c = (int)(t & (c3 - 1));
      int g = (int)(t >> lc3);
      float mu = st2[c] * inv_n;
      float var = st2[512 + c] * inv_n - mu * mu;
      float rs = rsqrtf(var + 1e-5f);
      float ga = g2[c], be = b2[c];
      const float* yp = bufB + (size_t)g * K * c3 + c;
      float m = -1e30f;
      for (int k = 0; k < K; ++k) {
        float v = ga * ((yp[(size_t)k * c3] - mu) * rs) + be;
        m = fmaxf(m, v);
      }
      outF[t] = m > 0.f ? m : 0.f;
    }
  }
}

// ---------------------------------------------------------------------------
extern "C" void kernel_launch(void* const* d_in, const int* in_sizes, int n_in,
                              void* d_out, int out_size, void* d_ws, size_t ws_size,
                              hipStream_t stream) {
  const float* pc = (const float*)d_in[0];
  float* out = (float*)d_out;
  char* wsb = (char*)d_ws;

  // ws: [0,1MB) ballidx; [1MB..) stats 12K floats + 4 u64 barrier counters;
  // [3MB,37MB) bufA; [37MB,104MB) bufB
  int* ballidx = (int*)wsb;
  float* stats = (float*)(wsb + ((size_t)1 << 20));
  unsigned long long* barcnt = (unsigned long long*)(stats + 12 * 1024);
  float* bufA = (float*)(wsb + ((size_t)3 << 20));
  float* bufB = (float*)(wsb + ((size_t)37 << 20));

  const int B = 8;
  static const int Ns[4] = {16384, 1024, 256, 64};
  static const int Ss[4] = {1024, 256, 64, 16};
  static const int Ks[4] = {32, 32, 16, 16};
  static const double Rr[4] = {0.02, 0.04, 0.06, 0.08};
  static const int Ci[4] = {3, 64, 128, 256};
  static const int mlp[4][4] = {{6,32,32,64},{67,64,64,128},{131,128,128,256},{259,256,256,512}};
  static const size_t ox[5] = {0, 393216, 417792, 423936, 425472};
  static const size_t of[5] = {425856, 819072, 1343360, 1605504, 1736576};

  split_zero_kernel<<<(B * 16384 + 255) / 256, 256, 0, stream>>>(
      pc, out + ox[0], out + of[0], B * 16384, stats, 12 * 1024 + 8);

  fps_mega_kernel<<<B, 1024, 0, stream>>>(out + ox[0], out + ox[1], out + ox[2],
                                          out + ox[3], out + ox[4]);

  for (int l = 0; l < 4; ++l) {
    const int N = Ns[l], S = Ss[l], K = Ks[l], ci = Ci[l];
    const float r2 = (float)(Rr[l] * Rr[l]);
    const int R = B * S * K;
    const float inv_n = 1.0f / (float)R;
    const float** wp = (const float**)alloca(9 * sizeof(float*));
    for (int j = 0; j < 9; ++j) wp[j] = (const float*)d_in[1 + l * 9 + j];
    layer_chain_kernel<<<NBLK, 256, 0, stream>>>(
        out + ox[l], out + of[l], out + ox[l + 1], ballidx, bufA, bufB,
        out + of[l + 1],
        wp[0], wp[1], wp[2], wp[3], wp[4], wp[5], wp[6], wp[7], wp[8],
        stats + (size_t)l * 3 * 1024, barcnt + l,
        N, S, K, ci, mlp[l][1], mlp[l][2], mlp[l][3], r2, inv_n);
  }
}